// Round 6
// baseline (230.068 us; speedup 1.0000x reference)
//
#include <hip/hip_runtime.h>

typedef float f32x4 __attribute__((ext_vector_type(4)));

// db4 reconstruction filters
#define G00 0.23037781330885523f
#define G01 0.7148465705525415f
#define G02 0.6308807679295904f
#define G03 -0.02798376941698385f
#define G04 -0.18703481171888114f
#define G05 0.030841381835986965f
#define G06 0.032883011666982945f
#define G07 -0.010597401784997278f

#define G10 -0.010597401784997278f
#define G11 -0.032883011666982945f
#define G12 0.030841381835986965f
#define G13 0.18703481171888114f
#define G14 -0.02798376941698385f
#define G15 -0.6308807679295904f
#define G16 0.7148465705525415f
#define G17 -0.23037781330885523f

// ---------------------------------------------------------------------------
// Fully-fused 3-axis inverse DWT level, single shared LDS buffer.
// Block = one output d-plane (blockIdx.y), 32 output h-rows (blockIdx.x),
// full W; batch via blockIdx.z + b0.
// Phase A: D-synthesis (global reads; 4 D-plane indices block-uniform)
//          -> smem as tl[4][20][N/4] f32x4 (exactly 5*512 elements at N=128)
// Phase B: H-synthesis tl -> REGISTERS (4 f32x4/thread), then after a
//          barrier stored back into smem as ul[2][32][N] (reuses tl space)
// Phase C: W-synthesis -> 32 rows x 2N floats of output (NT on final level)
// LDS = 40 KB (N=128) / 20 KB (N=64)  -> 3-4 blocks/CU vs 2 before.
// ---------------------------------------------------------------------------
template<int LOGN, bool NT>
__global__ __launch_bounds__(512) void idwt3_fused_k(
    const float* __restrict__ ll, const float* __restrict__ yh,
    float* __restrict__ out, int b0)
{
    constexpr int N = 1 << LOGN;
    constexpr int N4 = N / 4;
    constexpr int LOGN4 = LOGN - 2;
    constexpr int NN = N * N;
    constexpr size_t V = (size_t)N * N * N;
    constexpr int AELEMS = 4 * 20 * N4;       // 2560 (N=128) / 1280 (N=64)
    constexpr int BELEMS = 2 * 32 * N4;       // 2048 (N=128) / 1024 (N=64)
    constexpr int BITER  = BELEMS / 512;      // 4 / 2

    __shared__ f32x4 smem[AELEMS];            // tl then ul (ul fits: BELEMS<=AELEMS)

    const int tid  = threadIdx.x;
    const int tile = blockIdx.x;              // output h rows [32*tile, 32*tile+32)
    const int d    = blockIdx.y;              // output d-plane in [0, 2N)
    const int b    = b0 + (int)blockIdx.z;

    // D-synth params (block-uniform): out[d=2m+p] taps planes (m+p+1-t) mod N
    const int m = d >> 1, p = d & 1;
    const int P0 = (m + p + 1) & (N - 1);
    const int P1 = (m + p) & (N - 1);
    const int P2 = (m + p - 1 + N) & (N - 1);
    const int P3 = (m + p - 2 + N) & (N - 1);
    const float a0 = p ? G00 : G01, a1 = p ? G02 : G03;
    const float a2 = p ? G04 : G05, a3 = p ? G06 : G07;
    const float c0 = p ? G10 : G11, c1 = p ? G12 : G13;
    const float c2 = p ? G14 : G15, c3 = p ? G16 : G17;

    const int h0in = 16 * tile - 2;           // first halo h-row (wrapped)
    const float* llb = ll + (size_t)b * V;
    const float* yb  = yh + (size_t)b * 7 * V;

    // ---- Phase A: balanced over all pairs; element e = (pr*20 + r)*N4 + w4
    for (int e = tid; e < AELEMS; e += 512) {
        int w4 = e & (N4 - 1);
        int x  = e >> LOGN4;                  // pr*20 + r
        int pr = x / 20;
        int r  = x - 20 * pr;
        int hr = h0in + r;
        if (hr < 0) hr += N;
        if (hr >= N) hr -= N;
        const float* lo_base = (pr == 0) ? llb : (yb + (size_t)(2 * pr - 1) * V);
        const float* hi_base = yb + (size_t)(2 * pr) * V;
        int off = hr * N + w4 * 4;
        const float* lp = lo_base + off;
        const float* hp = hi_base + off;
        f32x4 acc = a0 * *(const f32x4*)(lp + (size_t)P0 * NN)
                  + a1 * *(const f32x4*)(lp + (size_t)P1 * NN)
                  + a2 * *(const f32x4*)(lp + (size_t)P2 * NN)
                  + a3 * *(const f32x4*)(lp + (size_t)P3 * NN)
                  + c0 * *(const f32x4*)(hp + (size_t)P0 * NN)
                  + c1 * *(const f32x4*)(hp + (size_t)P1 * NN)
                  + c2 * *(const f32x4*)(hp + (size_t)P2 * NN)
                  + c3 * *(const f32x4*)(hp + (size_t)P3 * NN);
        smem[e] = acc;
    }
    __syncthreads();

    // ---- Phase B: H synthesis into registers (static indexing)
    f32x4 ureg[BITER];
    #pragma unroll
    for (int it = 0; it < BITER; ++it) {
        int e = it * 512 + tid;
        int w4   = e & (N4 - 1);
        int rest = e >> LOGN4;
        int hl   = rest & 31;
        int qq   = rest >> 5;
        int ml = hl >> 1, pp = hl & 1;
        int ro = ml + pp + 3;
        float b0c = pp ? G00 : G01, b1c = pp ? G02 : G03;
        float b2c = pp ? G04 : G05, b3c = pp ? G06 : G07;
        float d0c = pp ? G10 : G11, d1c = pp ? G12 : G13;
        float d2c = pp ? G14 : G15, d3c = pp ? G16 : G17;
        int s0 = 2 * qq, s1 = s0 + 1;
        ureg[it] = b0c * smem[(s0 * 20 + ro    ) * N4 + w4]
                 + b1c * smem[(s0 * 20 + ro - 1) * N4 + w4]
                 + b2c * smem[(s0 * 20 + ro - 2) * N4 + w4]
                 + b3c * smem[(s0 * 20 + ro - 3) * N4 + w4]
                 + d0c * smem[(s1 * 20 + ro    ) * N4 + w4]
                 + d1c * smem[(s1 * 20 + ro - 1) * N4 + w4]
                 + d2c * smem[(s1 * 20 + ro - 2) * N4 + w4]
                 + d3c * smem[(s1 * 20 + ro - 3) * N4 + w4];
    }
    __syncthreads();
    // store ul over the tl space: ul[qq][hl][w] -> smem[(qq*32+hl)*N4 + w4] = e
    #pragma unroll
    for (int it = 0; it < BITER; ++it) {
        smem[it * 512 + tid] = ureg[it];
    }
    __syncthreads();

    // ---- Phase C: W synthesis + store (4 outputs = 2 pairs per iter)
    const float* ulf = (const float*)smem;
    float* orow_base = out + (((size_t)b * (2 * N) + d) * (2 * N) + (size_t)32 * tile) * (2 * N);
    for (int e = tid; e < 32 * (N / 2); e += 512) {
        int mw2 = e & (N / 2 - 1);
        int hl  = e >> (LOGN - 1);
        int mw  = mw2 * 2;
        const float* u0 = ulf + (size_t)hl * N;            // ul[0][hl][*]
        const float* u1 = ulf + (size_t)(32 + hl) * N;     // ul[1][hl][*]
        int mm2 = (mw - 2) & (N - 1), mm1 = (mw - 1) & (N - 1);
        int mp1 = (mw + 1) & (N - 1), mp2 = (mw + 2) & (N - 1), mp3 = (mw + 3) & (N - 1);
        float u0m2 = u0[mm2], u0m1 = u0[mm1], u00 = u0[mw];
        float u0p1 = u0[mp1], u0p2 = u0[mp2], u0p3 = u0[mp3];
        float u1m2 = u1[mm2], u1m1 = u1[mm1], u10 = u1[mw];
        float u1p1 = u1[mp1], u1p2 = u1[mp2], u1p3 = u1[mp3];
        f32x4 o;
        o.x = G01*u0p1 + G03*u00  + G05*u0m1 + G07*u0m2
            + G11*u1p1 + G13*u10  + G15*u1m1 + G17*u1m2;
        o.y = G00*u0p2 + G02*u0p1 + G04*u00  + G06*u0m1
            + G10*u1p2 + G12*u1p1 + G14*u10  + G16*u1m1;
        o.z = G01*u0p2 + G03*u0p1 + G05*u00  + G07*u0m1
            + G11*u1p2 + G13*u1p1 + G15*u10  + G17*u1m1;
        o.w = G00*u0p3 + G02*u0p2 + G04*u0p1 + G06*u00
            + G10*u1p3 + G12*u1p2 + G14*u1p1 + G16*u10;
        f32x4* dst = (f32x4*)(orow_base + (size_t)hl * (2 * N)) + mw2;
        if (NT) __builtin_nontemporal_store(o, dst);
        else    *dst = o;
    }
}

// ---------------------------------------------------------------------------

extern "C" void kernel_launch(void* const* d_in, const int* in_sizes, int n_in,
                              void* d_out, int out_size, void* d_ws, size_t ws_size,
                              hipStream_t stream)
{
    const float* yl  = (const float*)d_in[0];   // (4,1,64,64,64)
    const float* yh1 = (const float*)d_in[1];   // (4,7,128,128,128)
    const float* yh2 = (const float*)d_in[2];   // (4,7,64,64,64)
    float* outf = (float*)d_out;                // (4,1,256,256,256)
    float* ll1  = (float*)d_ws;                 // (4,128,128,128) = 33.5 MB scratch

    // ---- Level 1 (n=64 -> 128): fused, all batches; ll1 cached (re-read below)
    idwt3_fused_k<6, false><<<dim3(4, 128, 4), 512, 0, stream>>>(yl, yh2, ll1, 0);

    // ---- Level 2 (n=128 -> 256): fused, per-batch for L3 input residency;
    //      nontemporal final stores
    for (int b = 0; b < 4; ++b) {
        idwt3_fused_k<7, true><<<dim3(8, 256, 1), 512, 0, stream>>>(ll1, yh1, outf, b);
    }
}

// Round 7
// 206.478 us; speedup vs baseline: 1.1142x; 1.1142x over previous
//
#include <hip/hip_runtime.h>

typedef float f32x4 __attribute__((ext_vector_type(4)));

// db4 reconstruction filters
#define G00 0.23037781330885523f
#define G01 0.7148465705525415f
#define G02 0.6308807679295904f
#define G03 -0.02798376941698385f
#define G04 -0.18703481171888114f
#define G05 0.030841381835986965f
#define G06 0.032883011666982945f
#define G07 -0.010597401784997278f

#define G10 -0.010597401784997278f
#define G11 -0.032883011666982945f
#define G12 0.030841381835986965f
#define G13 0.18703481171888114f
#define G14 -0.02798376941698385f
#define G15 -0.6308807679295904f
#define G16 0.7148465705525415f
#define G17 -0.23037781330885523f

// ---------------------------------------------------------------------------
// Phase B (H-synth) + Phase C (W-synth + store) for ONE output d-plane,
// reading the t-tile tl[4][20][N/4] from smem, reusing smem for ul.
// Caller guarantees smem holds the full t-tile (barrier before call).
// On return, all threads have passed the final store loop (no trailing
// barrier — caller inserts one before reusing smem).
// ---------------------------------------------------------------------------
template<int LOGN, bool NT>
__device__ __forceinline__ void phaseBC(f32x4* smem, float* __restrict__ out,
                                        int b, int d, int tile, int tid)
{
    constexpr int N = 1 << LOGN;
    constexpr int N4 = N / 4;
    constexpr int LOGN4 = LOGN - 2;
    constexpr int BELEMS = 2 * 32 * N4;
    constexpr int BITER  = BELEMS / 512;

    // ---- Phase B: H synthesis into registers (static indexing)
    f32x4 ureg[BITER];
    #pragma unroll
    for (int it = 0; it < BITER; ++it) {
        int e = it * 512 + tid;
        int w4   = e & (N4 - 1);
        int rest = e >> LOGN4;
        int hl   = rest & 31;
        int qq   = rest >> 5;
        int ml = hl >> 1, pp = hl & 1;
        int ro = ml + pp + 3;
        float b0c = pp ? G00 : G01, b1c = pp ? G02 : G03;
        float b2c = pp ? G04 : G05, b3c = pp ? G06 : G07;
        float d0c = pp ? G10 : G11, d1c = pp ? G12 : G13;
        float d2c = pp ? G14 : G15, d3c = pp ? G16 : G17;
        int s0 = 2 * qq, s1 = s0 + 1;
        ureg[it] = b0c * smem[(s0 * 20 + ro    ) * N4 + w4]
                 + b1c * smem[(s0 * 20 + ro - 1) * N4 + w4]
                 + b2c * smem[(s0 * 20 + ro - 2) * N4 + w4]
                 + b3c * smem[(s0 * 20 + ro - 3) * N4 + w4]
                 + d0c * smem[(s1 * 20 + ro    ) * N4 + w4]
                 + d1c * smem[(s1 * 20 + ro - 1) * N4 + w4]
                 + d2c * smem[(s1 * 20 + ro - 2) * N4 + w4]
                 + d3c * smem[(s1 * 20 + ro - 3) * N4 + w4];
    }
    __syncthreads();
    // ul[qq][hl][w] -> smem[(qq*32+hl)*N4 + w4], same linear index e
    #pragma unroll
    for (int it = 0; it < BITER; ++it) {
        smem[it * 512 + tid] = ureg[it];
    }
    __syncthreads();

    // ---- Phase C: W synthesis + store (4 outputs = 2 pairs per iter)
    const float* ulf = (const float*)smem;
    float* orow_base = out + (((size_t)b * (2 * N) + d) * (2 * N) + (size_t)32 * tile) * (2 * N);
    for (int e = tid; e < 32 * (N / 2); e += 512) {
        int mw2 = e & (N / 2 - 1);
        int hl  = e >> (LOGN - 1);
        int mw  = mw2 * 2;
        const float* u0 = ulf + (size_t)hl * N;            // ul[0][hl][*]
        const float* u1 = ulf + (size_t)(32 + hl) * N;     // ul[1][hl][*]
        int mm2 = (mw - 2) & (N - 1), mm1 = (mw - 1) & (N - 1);
        int mp1 = (mw + 1) & (N - 1), mp2 = (mw + 2) & (N - 1), mp3 = (mw + 3) & (N - 1);
        float u0m2 = u0[mm2], u0m1 = u0[mm1], u00 = u0[mw];
        float u0p1 = u0[mp1], u0p2 = u0[mp2], u0p3 = u0[mp3];
        float u1m2 = u1[mm2], u1m1 = u1[mm1], u10 = u1[mw];
        float u1p1 = u1[mp1], u1p2 = u1[mp2], u1p3 = u1[mp3];
        f32x4 o;
        o.x = G01*u0p1 + G03*u00  + G05*u0m1 + G07*u0m2
            + G11*u1p1 + G13*u10  + G15*u1m1 + G17*u1m2;
        o.y = G00*u0p2 + G02*u0p1 + G04*u00  + G06*u0m1
            + G10*u1p2 + G12*u1p1 + G14*u10  + G16*u1m1;
        o.z = G01*u0p2 + G03*u0p1 + G05*u00  + G07*u0m1
            + G11*u1p2 + G13*u1p1 + G15*u10  + G17*u1m1;
        o.w = G00*u0p3 + G02*u0p2 + G04*u0p1 + G06*u00
            + G10*u1p3 + G12*u1p2 + G14*u1p1 + G16*u10;
        f32x4* dst = (f32x4*)(orow_base + (size_t)hl * (2 * N)) + mw2;
        if (NT) __builtin_nontemporal_store(o, dst);
        else    *dst = o;
    }
}

// ---------------------------------------------------------------------------
// Fully-fused 3-axis inverse DWT level; each block computes a d-PARITY PAIR
// (output planes d=2m and d=2m+1), sharing the 5 input D-planes {m-2..m+2}:
// Phase A does 10 f32x4 loads per t-element-pair (vs 16 for two blocks).
// Parity-0 t-tile -> LDS; parity-1 t-tile -> registers while parity-0 runs
// phases B/C, then swapped into the same LDS buffer. LDS stays 40 KB (N=128).
// ---------------------------------------------------------------------------
template<int LOGN, bool NT>
__global__ __launch_bounds__(512) void idwt3_fused2_k(
    const float* __restrict__ ll, const float* __restrict__ yh,
    float* __restrict__ out, int b0)
{
    constexpr int N = 1 << LOGN;
    constexpr int N4 = N / 4;
    constexpr int LOGN4 = LOGN - 2;
    constexpr int NN = N * N;
    constexpr size_t V = (size_t)N * N * N;
    constexpr int AELEMS = 4 * 20 * N4;            // 2560 (N=128) / 1280 (N=64)
    constexpr int AITER  = (AELEMS + 511) / 512;   // 5 / 3 (last partial at N=64)

    __shared__ f32x4 smem[AELEMS];

    const int tid  = threadIdx.x;
    const int tile = blockIdx.x;              // output h rows [32*tile, 32*tile+32)
    const int mD   = blockIdx.y;              // d-pair index m in [0, N)
    const int b    = b0 + (int)blockIdx.z;

    // Shared D-planes {m-2 .. m+2} (block-uniform)
    const size_t q0 = (size_t)((mD - 2 + N) & (N - 1)) * NN;   // m-2
    const size_t q1 = (size_t)((mD - 1 + N) & (N - 1)) * NN;   // m-1
    const size_t q2 = (size_t)( mD                    ) * NN;  // m
    const size_t q3 = (size_t)((mD + 1) & (N - 1)) * NN;       // m+1
    const size_t q4 = (size_t)((mD + 2) & (N - 1)) * NN;       // m+2

    const int h0in = 16 * tile - 2;           // first halo h-row (wrapped)
    const float* llb = ll + (size_t)b * V;
    const float* yb  = yh + (size_t)b * 7 * V;

    // ---- Phase A: both parities from 10 loads; p0 -> smem, p1 -> registers
    f32x4 treg[AITER];
    #pragma unroll
    for (int it = 0; it < AITER; ++it) {
        int e = it * 512 + tid;
        if (AELEMS % 512 != 0 && e >= AELEMS) continue;
        int w4 = e & (N4 - 1);
        int x  = e >> LOGN4;                  // pr*20 + r
        int pr = x / 20;
        int r  = x - 20 * pr;
        int hr = h0in + r;
        if (hr < 0) hr += N;
        if (hr >= N) hr -= N;
        const float* lo_base = (pr == 0) ? llb : (yb + (size_t)(2 * pr - 1) * V);
        const float* hi_base = yb + (size_t)(2 * pr) * V;
        int off = hr * N + w4 * 4;
        const float* lp = lo_base + off;
        const float* hp = hi_base + off;
        f32x4 Lm2 = *(const f32x4*)(lp + q0);
        f32x4 Lm1 = *(const f32x4*)(lp + q1);
        f32x4 L0c = *(const f32x4*)(lp + q2);
        f32x4 Lp1 = *(const f32x4*)(lp + q3);
        f32x4 Lp2 = *(const f32x4*)(lp + q4);
        f32x4 Hm2 = *(const f32x4*)(hp + q0);
        f32x4 Hm1 = *(const f32x4*)(hp + q1);
        f32x4 H0c = *(const f32x4*)(hp + q2);
        f32x4 Hp1 = *(const f32x4*)(hp + q3);
        f32x4 Hp2 = *(const f32x4*)(hp + q4);
        // p=0: taps g0[1,3,5,7] at planes m+1,m,m-1,m-2
        smem[e] = G01*Lp1 + G03*L0c + G05*Lm1 + G07*Lm2
                + G11*Hp1 + G13*H0c + G15*Hm1 + G17*Hm2;
        // p=1: taps g0[0,2,4,6] at planes m+2,m+1,m,m-1
        treg[it] = G00*Lp2 + G02*Lp1 + G04*L0c + G06*Lm1
                 + G10*Hp2 + G12*Hp1 + G14*H0c + G16*Hm1;
    }
    __syncthreads();

    // ---- parity 0: B/C pipeline for d = 2m
    phaseBC<LOGN, NT>(smem, out, b, 2 * mD, tile, tid);
    __syncthreads();                          // all Phase-C reads of smem done

    // ---- swap parity-1 t-tile into LDS
    #pragma unroll
    for (int it = 0; it < AITER; ++it) {
        int e = it * 512 + tid;
        if (AELEMS % 512 != 0 && e >= AELEMS) continue;
        smem[e] = treg[it];
    }
    __syncthreads();

    // ---- parity 1: B/C pipeline for d = 2m+1
    phaseBC<LOGN, NT>(smem, out, b, 2 * mD + 1, tile, tid);
}

// ---------------------------------------------------------------------------

extern "C" void kernel_launch(void* const* d_in, const int* in_sizes, int n_in,
                              void* d_out, int out_size, void* d_ws, size_t ws_size,
                              hipStream_t stream)
{
    const float* yl  = (const float*)d_in[0];   // (4,1,64,64,64)
    const float* yh1 = (const float*)d_in[1];   // (4,7,128,128,128)
    const float* yh2 = (const float*)d_in[2];   // (4,7,64,64,64)
    float* outf = (float*)d_out;                // (4,1,256,256,256)
    float* ll1  = (float*)d_ws;                 // (4,128,128,128) = 33.5 MB scratch

    // ---- Level 1 (n=64 -> 128): fused, all batches; ll1 cached (re-read below)
    idwt3_fused2_k<6, false><<<dim3(4, 64, 4), 512, 0, stream>>>(yl, yh2, ll1, 0);

    // ---- Level 2 (n=128 -> 256): fused, per-batch for L3 input residency;
    //      nontemporal final stores
    for (int b = 0; b < 4; ++b) {
        idwt3_fused2_k<7, true><<<dim3(8, 128, 1), 512, 0, stream>>>(ll1, yh1, outf, b);
    }
}